// Round 1
// baseline (1586.806 us; speedup 1.0000x reference)
//
#include <hip/hip_runtime.h>
#include <math.h>

#define NN   100000
#define HH   128
#define EXTD 768
#define EE   1600000
#define LNEPS 1e-5f

#define BM 64
#define BN 128
#define BK 16

// ---------------- CSR build ----------------

__global__ void k_init(int* __restrict__ deg, int* __restrict__ counter) {
    int i = blockIdx.x * 256 + threadIdx.x;
    if (i < NN) deg[i] = 1;            // self loop contributes 1 to degree
    if (i == 0) *counter = 0;
}

__global__ void k_count(const int* __restrict__ dst, int* __restrict__ deg) {
    int e = blockIdx.x * 256 + threadIdx.x;
    if (e < EE) atomicAdd(&deg[dst[e]], 1);
}

__global__ void k_offsets(const int* __restrict__ deg, float* __restrict__ dinv,
                          int* __restrict__ rowstart, int* __restrict__ cursor,
                          int* __restrict__ counter) {
    int i = blockIdx.x * 256 + threadIdx.x;
    if (i < NN) {
        int d = deg[i];
        dinv[i] = rsqrtf((float)d);
        int rs = atomicAdd(counter, d - 1);   // in-degree excluding self loop
        rowstart[i] = rs;
        cursor[i]   = rs;
    }
}

__global__ void k_fill(const int* __restrict__ src, const int* __restrict__ dst,
                       int* __restrict__ cursor, int* __restrict__ col) {
    int e = blockIdx.x * 256 + threadIdx.x;
    if (e < EE) {
        int d = dst[e];
        int p = atomicAdd(&cursor[d], 1);
        col[p] = src[e];
    }
}

// ---------------- GEMM: C[N x 128] = A[N x K] @ W[K x 128] (+bias) (+LN+ReLU) ----------------
// LNRELU: fuse LayerNorm (over the 128 output cols) + ReLU into epilogue.
// CONCAT: A row = concat(A0 row [128], A1 row [128]), K must be 256.

template<int LNRELU, int CONCAT>
__global__ __launch_bounds__(256)
void k_gemm(const float* __restrict__ A0, const float* __restrict__ A1,
            const float* __restrict__ W,  const float* __restrict__ bias,
            const float* __restrict__ lng, const float* __restrict__ lnb,
            float* __restrict__ C, int K)
{
    __shared__ float As[BK][BM + 4];   // +4 pad: keeps 16B alignment, breaks bank conflicts
    __shared__ float Bs[BK][BN + 4];

    const int tid  = threadIdx.x;
    const int row0 = blockIdx.x * BM;
    const int ty = tid >> 4;          // 0..15 -> 4 rows each
    const int tx = tid & 15;          // 0..15 -> 8 cols each
    const int ar = tid >> 2;          // 0..63  A-load row
    const int ak = (tid & 3) * 4;     // A-load k offset (float4)
    const int bk = ty;                // B-load k row
    const int bj = tx * 8;            // B-load col offset (2x float4)
    const int grow = row0 + ar;
    const int c0 = tx * 8;

    float acc[4][8];
#pragma unroll
    for (int i = 0; i < 4; ++i)
#pragma unroll
        for (int j = 0; j < 8; ++j) acc[i][j] = 0.f;

    for (int k0 = 0; k0 < K; k0 += BK) {
        float4 av = make_float4(0.f, 0.f, 0.f, 0.f);
        if (grow < NN) {
            int kk = k0 + ak;
            const float* ap;
            if (CONCAT) {
                ap = (kk < HH) ? (A0 + (size_t)grow * HH + kk)
                               : (A1 + (size_t)grow * HH + (kk - HH));
            } else {
                ap = A0 + (size_t)grow * K + kk;
            }
            av = *(const float4*)ap;
        }
        const float4* wp = (const float4*)(W + (size_t)(k0 + bk) * BN + bj);
        const float4 bv0 = wp[0];
        const float4 bv1 = wp[1];

        __syncthreads();
        As[ak + 0][ar] = av.x;
        As[ak + 1][ar] = av.y;
        As[ak + 2][ar] = av.z;
        As[ak + 3][ar] = av.w;
        *(float4*)&Bs[bk][bj]     = bv0;
        *(float4*)&Bs[bk][bj + 4] = bv1;
        __syncthreads();

#pragma unroll
        for (int k = 0; k < BK; ++k) {
            const float4 a  = *(const float4*)&As[k][ty * 4];
            const float4 b0 = *(const float4*)&Bs[k][tx * 8];
            const float4 b1 = *(const float4*)&Bs[k][tx * 8 + 4];
            const float aa[4] = {a.x, a.y, a.z, a.w};
            const float bb[8] = {b0.x, b0.y, b0.z, b0.w, b1.x, b1.y, b1.z, b1.w};
#pragma unroll
            for (int i = 0; i < 4; ++i)
#pragma unroll
                for (int j = 0; j < 8; ++j)
                    acc[i][j] = fmaf(aa[i], bb[j], acc[i][j]);
        }
    }

    // bias (pre-LN for encoder; plain bias otherwise)
    if (bias != nullptr) {
        const float4 q0 = *(const float4*)&bias[c0];
        const float4 q1 = *(const float4*)&bias[c0 + 4];
        const float qb[8] = {q0.x, q0.y, q0.z, q0.w, q1.x, q1.y, q1.z, q1.w};
#pragma unroll
        for (int i = 0; i < 4; ++i)
#pragma unroll
            for (int j = 0; j < 8; ++j) acc[i][j] += qb[j];
    }

    if (LNRELU) {
        __shared__ float red1[BM][17];
        __shared__ float red2[BM][17];
        __shared__ float muS[BM];
        __shared__ float rsS[BM];
#pragma unroll
        for (int i = 0; i < 4; ++i) {
            float s1 = 0.f, s2 = 0.f;
#pragma unroll
            for (int j = 0; j < 8; ++j) { s1 += acc[i][j]; s2 = fmaf(acc[i][j], acc[i][j], s2); }
            red1[ty * 4 + i][tx] = s1;
            red2[ty * 4 + i][tx] = s2;
        }
        __syncthreads();
        if (tid < BM) {
            float a = 0.f, b = 0.f;
#pragma unroll
            for (int t = 0; t < 16; ++t) { a += red1[tid][t]; b += red2[tid][t]; }
            float mu  = a * (1.0f / HH);
            float var = fmaf(-mu, mu, b * (1.0f / HH));
            muS[tid] = mu;
            rsS[tid] = rsqrtf(var + LNEPS);
        }
        __syncthreads();
        const float4 g0 = *(const float4*)&lng[c0];
        const float4 g1 = *(const float4*)&lng[c0 + 4];
        const float4 h0 = *(const float4*)&lnb[c0];
        const float4 h1 = *(const float4*)&lnb[c0 + 4];
        const float gg[8] = {g0.x, g0.y, g0.z, g0.w, g1.x, g1.y, g1.z, g1.w};
        const float hh[8] = {h0.x, h0.y, h0.z, h0.w, h1.x, h1.y, h1.z, h1.w};
#pragma unroll
        for (int i = 0; i < 4; ++i) {
            const float mu = muS[ty * 4 + i];
            const float rs = rsS[ty * 4 + i];
#pragma unroll
            for (int j = 0; j < 8; ++j) {
                float v = (acc[i][j] - mu) * rs;
                v = fmaf(v, gg[j], hh[j]);
                acc[i][j] = fmaxf(v, 0.f);
            }
        }
    }

#pragma unroll
    for (int i = 0; i < 4; ++i) {
        int r = row0 + ty * 4 + i;
        if (r < NN) {
            float4 o0 = make_float4(acc[i][0], acc[i][1], acc[i][2], acc[i][3]);
            float4 o1 = make_float4(acc[i][4], acc[i][5], acc[i][6], acc[i][7]);
            *(float4*)&C[(size_t)r * BN + c0]     = o0;
            *(float4*)&C[(size_t)r * BN + c0 + 4] = o1;
        }
    }
}

// ---------------- SpMM: out[d] = dinv[d] * (sum_e dinv[src] * Y[src] + dinv[d]*Y[d]) + bias ----------------
// One wave (64 lanes) per destination node; each lane owns 2 channels.

__global__ __launch_bounds__(256)
void k_spmm(const float* __restrict__ Y, const int* __restrict__ col,
            const int* __restrict__ rs, const int* __restrict__ re,
            const float* __restrict__ dinv, const float* __restrict__ bias,
            float* __restrict__ out, int dorelu)
{
    int gid  = blockIdx.x * blockDim.x + threadIdx.x;
    int node = gid >> 6;
    int lane = threadIdx.x & 63;
    if (node >= NN) return;

    const int beg = rs[node];
    const int end = re[node];
    const float di = dinv[node];

    float2 acc;
    {   // self loop: norm = di*di (outer di applied at the end)
        const float2 v = *(const float2*)(Y + (size_t)node * HH + lane * 2);
        acc.x = di * v.x;
        acc.y = di * v.y;
    }
    for (int e = beg; e < end; ++e) {
        const int s = col[e];
        const float w = dinv[s];
        const float2 v = *(const float2*)(Y + (size_t)s * HH + lane * 2);
        acc.x = fmaf(w, v.x, acc.x);
        acc.y = fmaf(w, v.y, acc.y);
    }
    float ox = fmaf(di, acc.x, bias[lane * 2]);
    float oy = fmaf(di, acc.y, bias[lane * 2 + 1]);
    if (dorelu) { ox = fmaxf(ox, 0.f); oy = fmaxf(oy, 0.f); }
    float2 o; o.x = ox; o.y = oy;
    *(float2*)(out + (size_t)node * HH + lane * 2) = o;
}

// ---------------- launch ----------------

extern "C" void kernel_launch(void* const* d_in, const int* in_sizes, int n_in,
                              void* d_out, int out_size, void* d_ws, size_t ws_size,
                              hipStream_t stream)
{
    const int*   ei    = (const int*)d_in[0];
    const float* ext   = (const float*)d_in[1];
    const float* emb   = (const float*)d_in[2];
    const float* encW  = (const float*)d_in[3];
    const float* encB  = (const float*)d_in[4];
    const float* lng   = (const float*)d_in[5];
    const float* lnb   = (const float*)d_in[6];
    const float* projW = (const float*)d_in[7];
    const float* projB = (const float*)d_in[8];
    const float* W0    = (const float*)d_in[9];
    const float* b0    = (const float*)d_in[10];
    const float* W1    = (const float*)d_in[11];
    const float* b1    = (const float*)d_in[12];
    const float* W2    = (const float*)d_in[13];
    const float* b2    = (const float*)d_in[14];

    const int* srcI = ei;        // edge_index[0]
    const int* dstI = ei + EE;   // edge_index[1]

    char* w = (char*)d_ws;
    size_t off = 0;
    auto alloc = [&](size_t bytes) -> void* {
        void* p = w + off;
        off += (bytes + 255) & ~(size_t)255;
        return p;
    };
    int*   deg      = (int*)alloc((size_t)NN * 4);
    float* dinv     = (float*)alloc((size_t)NN * 4);
    int*   rowstart = (int*)alloc((size_t)NN * 4);
    int*   cursor   = (int*)alloc((size_t)NN * 4);
    int*   counter  = (int*)alloc(256);
    int*   col      = (int*)alloc((size_t)EE * 4);
    float* bufA     = (float*)alloc((size_t)NN * HH * 4);
    float* bufB     = (float*)alloc((size_t)NN * HH * 4);

    const int gN = (NN + 255) / 256;
    const int gE = (EE + 255) / 256;
    const int gG = (NN + BM - 1) / BM;
    const int gS = (NN + 3) / 4;       // 4 waves (nodes) per 256-thread block

    k_init   <<<gN, 256, 0, stream>>>(deg, counter);
    k_count  <<<gE, 256, 0, stream>>>(dstI, deg);
    k_offsets<<<gN, 256, 0, stream>>>(deg, dinv, rowstart, cursor, counter);
    k_fill   <<<gE, 256, 0, stream>>>(srcI, dstI, cursor, col);

    // feat = relu(LN(ext @ encW + encB))            -> bufA
    k_gemm<1, 0><<<gG, 256, 0, stream>>>(ext, nullptr, encW, encB, lng, lnb, bufA, EXTD);
    // x = concat(emb, feat) @ projW + projB         -> bufB
    k_gemm<0, 1><<<gG, 256, 0, stream>>>(emb, bufA, projW, projB, nullptr, nullptr, bufB, 2 * HH);
    // y = x @ W0                                    -> bufA
    k_gemm<0, 0><<<gG, 256, 0, stream>>>(bufB, nullptr, W0, nullptr, nullptr, nullptr, bufA, HH);
    // x = relu(spmm(y) + b0)                        -> bufB
    k_spmm<<<gS, 256, 0, stream>>>(bufA, col, rowstart, cursor, dinv, b0, bufB, 1);
    // y = x @ W1                                    -> bufA
    k_gemm<0, 0><<<gG, 256, 0, stream>>>(bufB, nullptr, W1, nullptr, nullptr, nullptr, bufA, HH);
    // x = relu(spmm(y) + b1)                        -> bufB
    k_spmm<<<gS, 256, 0, stream>>>(bufA, col, rowstart, cursor, dinv, b1, bufB, 1);
    // y = x @ W2                                    -> bufA
    k_gemm<0, 0><<<gG, 256, 0, stream>>>(bufB, nullptr, W2, nullptr, nullptr, nullptr, bufA, HH);
    // out = spmm(y) + b2                            -> d_out
    k_spmm<<<gS, 256, 0, stream>>>(bufA, col, rowstart, cursor, dinv, b2, (float*)d_out, 0);
}